// Round 12
// baseline (91.908 us; speedup 1.0000x reference)
//
#include <hip/hip_runtime.h>
#include <math.h>

#define NMODES 6400
#define TB     128                // 2 waves per block
#define MPT    10                 // modes per thread (5 float2 pairs)
#define NPAIR  5
#define MG     5                  // mode groups: TB*MPT*MG == NMODES
#define BATCH  7                  // samples per inner batch
#define TC     84                 // samples per block (two 42-sample phases)
#define TCH    42                 // samples per LDS phase
#define NORMB  256                // norm kernel block size

typedef float v2f __attribute__((ext_vector_type(2)));

static __device__ __forceinline__ float softplusf(float x) {
    return log1pf(expf(-fabsf(x))) + fmaxf(x, 0.0f);
}
static __device__ __forceinline__ float sigmoidf(float x) {
    return 1.0f / (1.0f + expf(-x));
}

// Per-mode constants + stride-zero of out + zero of peak/done.
// Math byte-identical to the round-3/9/11 verified setup.
__global__ void setup_zero_kernel(const float* __restrict__ mu_raw,
                                  const float* __restrict__ Dmu_raw,
                                  const float* __restrict__ T0mu_raw,
                                  const float* __restrict__ Ly_raw,
                                  const float* __restrict__ xo_raw,
                                  const float* __restrict__ yo_raw,
                                  float* __restrict__ wsA,
                                  float* __restrict__ wsW,
                                  float* __restrict__ wsS,
                                  float* __restrict__ wsCW,
                                  float* __restrict__ wsSW,
                                  unsigned int* __restrict__ peak,
                                  unsigned int* __restrict__ done,
                                  float* __restrict__ out, int T)
{
    int id = blockIdx.x * blockDim.x + threadIdx.x;
    int gsz = gridDim.x * blockDim.x;
    for (int i = id; i < T; i += gsz) out[i] = 0.0f;
    if (id == 0) { *peak = 0u; *done = 0u; }
    if (id >= NMODES) return;

    const float KF   = 1.0f / 44100.0f;
    const float PI_F = (float)M_PI;
    const double om2sq = (2.0 * M_PI * 500.0) * (2.0 * M_PI * 500.0);
    const float ALPHA_F  = (float)(3.0 * M_LN10 / om2sq * (om2sq / 6.0));
    const float BETA_F   = (float)(3.0 * M_LN10 / om2sq * (1.0 - 1.0 / 6.0));
    const float MAX_OM_F = (float)(10000.0 * 2.0 * M_PI);
    const float MIN_OM_F = (float)(20.0 * 2.0 * M_PI);
    const float KK_F     = (float)((1.0 / 44100.0) * (1.0 / 44100.0));

    float mu   = (softplusf(mu_raw[0])   + 1e-4f) * 2.43f;
    float Dmu  = (softplusf(Dmu_raw[0])  + 1e-4f) * 0.002452f;
    float T0mu = (softplusf(T0mu_raw[0]) + 1e-4f) * 0.004115f;
    float Ly   = 1.1f + 2.9f * sigmoidf(Ly_raw[0]);
    float xo   = 0.245f + 0.255f * sigmoidf(xo_raw[0]);
    float yo   = __fadd_rn(__fmul_rn(0.51f, Ly),
                           __fmul_rn(__fmul_rn(0.49f, Ly), sigmoidf(yo_raw[0])));

    float mf = (float)(id / 80 + 1);
    float nf = (float)(id % 80 + 1);

    float am = __fmul_rn(__fmul_rn(mf, PI_F), 2.0f);
    float bn = __fdiv_rn(__fmul_rn(nf, PI_F), Ly);
    float g1 = __fadd_rn(__fmul_rn(am, am), __fmul_rn(bn, bn));
    float omega_sq = __fadd_rn(__fmul_rn(T0mu, g1),
                               __fmul_rn(__fmul_rn(Dmu, g1), g1));
    float omega = sqrtf(fmaxf(omega_sq, 0.0f));
    float valid = (omega <= MAX_OM_F && omega >= MIN_OM_F) ? 1.0f : 0.0f;

    float xi_pi = (float)(0.05 * M_PI);
    float yi = __fmul_rn(0.1f, Ly);
    float InW = __fmul_rn(
        cosf(__fmul_rn(__fmul_rn(xi_pi, mf), 2.0f)),
        cosf(__fdiv_rn(__fmul_rn(__fmul_rn(yi, PI_F), nf), Ly)));
    float OutW = __fmul_rn(
        cosf(__fmul_rn(__fmul_rn(__fmul_rn(xo, PI_F), mf), 2.0f)),
        cosf(__fdiv_rn(__fmul_rn(__fmul_rn(yo, PI_F), nf), Ly)));

    float sigma = __fadd_rn(ALPHA_F, __fmul_rn(BETA_F, __fmul_rn(omega, omega)));
    float ms = __fmul_rn(__fmul_rn(__fmul_rn(0.25f, mu), 0.5f), Ly);
    float P = __fmul_rn(
        __fdiv_rn(__fmul_rn(__fmul_rn(__fmul_rn(OutW, InW), KK_F),
                            expf(__fmul_rn(-sigma, KF))),
                  ms),
        valid);
    float den = __fadd_rn(sinf(__fmul_rn(omega, KF)), 1e-8f);
    float A = __fdiv_rn(P, den);

    const double Kd = 1.0 / 44100.0;
    double th = (double)omega * Kd;
    double dd = exp(-(double)sigma * Kd);
    wsA[id]  = A;
    wsW[id]  = omega;
    wsS[id]  = sigma;
    wsCW[id] = (float)(dd * cos(th));
    wsSW[id] = (float)(dd * sin(th));
}

// R11 Goertzel body with TC=84: ONE f64 seed + constant-load per block
// amortized over TWO 42-sample LDS phases (per-block fixed cost halved,
// block count 2625 -> 1315). LDS stays [42][130] = 21.8 KB (7 blocks/CU
// cap; 5.1 needed -> fully co-residentable). Owner-lane reduce + guarded
// atomicAdd after each phase, byte-identical reduce pattern to R3/R11.
__global__ __launch_bounds__(TB) void accum_kernel(
    const float* __restrict__ wsA,
    const float* __restrict__ wsW,
    const float* __restrict__ wsS,
    const float* __restrict__ wsCW,
    const float* __restrict__ wsSW,
    float* __restrict__ out, int T)
{
    __shared__ __align__(16) float lds[TCH][TB + 2];

    const int tid  = threadIdx.x;
    const int t0   = blockIdx.x * TC;
    const int base = blockIdx.y * (TB * MPT);
    const int wv   = tid >> 6;
    const int lane = tid & 63;

    const float  KF     = 1.0f / 44100.0f;
    const double Kd     = 1.0 / 44100.0;
    const double TWO_PI = 6.283185307179586476925286766559;
    const double I2PI   = 0.15915494309189533576888376337251;

    v2f Y0[NPAIR], Y1[NPAIR], C1[NPAIR], C2[NPAIR];
    #pragma unroll
    for (int p = 0; p < NPAIR; ++p) {
        int m = base + p * (TB * 2) + tid * 2;     // even -> 8B aligned
        v2f CW = *(const v2f*)(wsCW + m);
        v2f SW = *(const v2f*)(wsSW + m);
        v2f A  = *(const v2f*)(wsA + m);
        v2f w  = *(const v2f*)(wsW + m);
        v2f sg = *(const v2f*)(wsS + m);
        v2f S, C;
        #pragma unroll
        for (int k = 0; k < 2; ++k) {
            double ph = (double)t0 * (double)w[k] * Kd;
            double q  = rint(ph * I2PI);
            float  r  = (float)fma(-q, TWO_PI, ph);
            float s0, c0;
            __sincosf(r, &s0, &c0);
            float env = A[k] * __expf(-sg[k] * (float)(t0 - 1) * KF);
            S[k] = env * s0;
            C[k] = env * c0;
        }
        Y0[p] = S;                                          // v_{t0}
        Y1[p] = __builtin_elementwise_fma(S, CW, C * SW);   // v_{t0+1}
        C1[p] = CW + CW;                                    // 2 d cos(th)
        C2[p] = __builtin_elementwise_fma(CW, CW, SW * SW); // d^2
    }

    const int  s_own = wv * (TCH / 2) + lane;      // wave0 rows 0-20, wave1 21-41
    const bool own   = (lane < TCH / 2);

    #pragma unroll 1
    for (int ph2 = 0; ph2 < 2; ++ph2) {
        #pragma unroll 1
        for (int it = 0; it < TCH; it += BATCH) {
            #pragma unroll
            for (int b = 0; b < BATCH; ++b) {
                // per-thread (10-mode) partial for this sample (current = Y0)
                v2f s01 = Y0[0] + Y0[1];
                v2f s23 = Y0[2] + Y0[3];
                v2f sp  = (s01 + s23) + Y0[4];
                lds[it + b][tid] = sp[0] + sp[1];
                // advance: y_{n+1} = c1*y_n - c2*y_{n-1} (2 packed ops/pair)
                #pragma unroll
                for (int p = 0; p < NPAIR; ++p) {
                    v2f yn = __builtin_elementwise_fma(C1[p], Y1[p], -(C2[p] * Y0[p]));
                    Y0[p] = Y1[p];
                    Y1[p] = yn;
                }
            }
        }
        __syncthreads();                           // phase writes visible

        if (own) {
            v2f z = {0.0f, 0.0f};
            #pragma unroll
            for (int r = 0; r < TB / 2; ++r)
                z += *(const v2f*)&lds[s_own][2 * r];
            int t = t0 + ph2 * TCH + s_own;
            if (t < T) atomicAdd(&out[t], z[0] + z[1]);
        }
        __syncthreads();                           // reads done before reuse
    }
}

// R9/R11-field-verified fused max+div: 44 uniform co-resident blocks, local
// max from registers -> atomicMax(peak) -> release-add(done) -> short
// acquire poll -> divide own segment from registers already loaded.
__global__ __launch_bounds__(NORMB) void norm_kernel(
    float* __restrict__ out,
    unsigned int* peak,
    unsigned int* done, int T, int nblk)
{
    __shared__ float red[NORMB / 64];
    __shared__ float pks;

    int i = blockIdx.x * NORMB + threadIdx.x;      // pair index
    v2f v = {0.0f, 0.0f};
    bool full = (2 * i + 1 < T), half = (!full && 2 * i < T);
    if (full)      v = *(const v2f*)(out + 2 * i);
    else if (half) v[0] = out[2 * i];

    float mx = fmaxf(fabsf(v[0]), fabsf(v[1]));
    #pragma unroll
    for (int off = 32; off > 0; off >>= 1)
        mx = fmaxf(mx, __shfl_xor(mx, off, 64));
    int lane = threadIdx.x & 63, wv = threadIdx.x >> 6;
    if (lane == 0) red[wv] = mx;
    __syncthreads();

    if (threadIdx.x == 0) {
        float m = red[0];
        #pragma unroll
        for (int k = 1; k < NORMB / 64; ++k) m = fmaxf(m, red[k]);
        atomicMax(peak, __float_as_uint(m));       // m >= 0: bits monotone
        __hip_atomic_fetch_add(done, 1u, __ATOMIC_RELEASE,
                               __HIP_MEMORY_SCOPE_AGENT);
        unsigned int x;
        do {
            __builtin_amdgcn_s_sleep(2);
            x = __hip_atomic_load(done, __ATOMIC_ACQUIRE,
                                  __HIP_MEMORY_SCOPE_AGENT);
        } while (x < (unsigned int)nblk);
        pks = __uint_as_float(__hip_atomic_load(peak, __ATOMIC_RELAXED,
                                                __HIP_MEMORY_SCOPE_AGENT)) + 1e-8f;
    }
    __syncthreads();

    float pk = pks;
    if (full) {
        v[0] = __fdiv_rn(v[0], pk);
        v[1] = __fdiv_rn(v[1], pk);
        *(v2f*)(out + 2 * i) = v;
    } else if (half) {
        out[2 * i] = __fdiv_rn(v[0], pk);
    }
}

extern "C" void kernel_launch(void* const* d_in, const int* in_sizes, int n_in,
                              void* d_out, int out_size, void* d_ws, size_t ws_size,
                              hipStream_t stream)
{
    const float* mu   = (const float*)d_in[0];
    const float* Dmu  = (const float*)d_in[1];
    const float* T0mu = (const float*)d_in[2];
    const float* Lyr  = (const float*)d_in[3];
    const float* xor_ = (const float*)d_in[4];
    const float* yor_ = (const float*)d_in[5];
    float* out = (float*)d_out;

    float* ws   = (float*)d_ws;
    float* wsA  = ws;
    float* wsW  = ws + NMODES;
    float* wsS  = ws + 2 * NMODES;
    float* wsCW = ws + 3 * NMODES;
    float* wsSW = ws + 4 * NMODES;
    unsigned int* peak = (unsigned int*)(ws + 5 * NMODES);
    unsigned int* done = (unsigned int*)(ws + 5 * NMODES + 1);

    int T = out_size;
    int tchunks = (T + TC - 1) / TC;               // 263 at T=22050
    int npairs  = (T + 1) / 2;
    int nblk    = (npairs + NORMB - 1) / NORMB;    // 44 at T=22050

    setup_zero_kernel<<<(NMODES + 255) / 256, 256, 0, stream>>>(
        mu, Dmu, T0mu, Lyr, xor_, yor_, wsA, wsW, wsS, wsCW, wsSW,
        peak, done, out, T);
    accum_kernel<<<dim3(tchunks, MG), TB, 0, stream>>>(
        wsA, wsW, wsS, wsCW, wsSW, out, T);
    norm_kernel<<<nblk, NORMB, 0, stream>>>(out, peak, done, T, nblk);
}

// Round 13
// 88.898 us; speedup vs baseline: 1.0339x; 1.0339x over previous
//
#include <hip/hip_runtime.h>
#include <math.h>

#define NMODES 6400
#define TB     128                // 2 waves per block
#define MPT    10                 // modes per thread (5 float2 pairs)
#define NPAIR  5
#define MG     5                  // mode groups: TB*MPT*MG == NMODES
#define BATCH  6                  // samples per inner batch
#define TC     42                 // samples per time-chunk (22050 = 525*42)
#define NORMB  256                // norm kernel block size

typedef float v2f __attribute__((ext_vector_type(2)));

static __device__ __forceinline__ float softplusf(float x) {
    return log1pf(expf(-fabsf(x))) + fmaxf(x, 0.0f);
}
static __device__ __forceinline__ float sigmoidf(float x) {
    return 1.0f / (1.0f + expf(-x));
}

// Per-mode constants + stride-zero of out + zero of peak/done.
// Math byte-identical to the round-3/9/11 verified setup.
__global__ void setup_zero_kernel(const float* __restrict__ mu_raw,
                                  const float* __restrict__ Dmu_raw,
                                  const float* __restrict__ T0mu_raw,
                                  const float* __restrict__ Ly_raw,
                                  const float* __restrict__ xo_raw,
                                  const float* __restrict__ yo_raw,
                                  float* __restrict__ wsA,
                                  float* __restrict__ wsW,
                                  float* __restrict__ wsS,
                                  float* __restrict__ wsCW,
                                  float* __restrict__ wsSW,
                                  unsigned int* __restrict__ peak,
                                  unsigned int* __restrict__ done,
                                  float* __restrict__ out, int T)
{
    int id = blockIdx.x * blockDim.x + threadIdx.x;
    int gsz = gridDim.x * blockDim.x;
    for (int i = id; i < T; i += gsz) out[i] = 0.0f;
    if (id == 0) { *peak = 0u; *done = 0u; }
    if (id >= NMODES) return;

    const float KF   = 1.0f / 44100.0f;
    const float PI_F = (float)M_PI;
    const double om2sq = (2.0 * M_PI * 500.0) * (2.0 * M_PI * 500.0);
    const float ALPHA_F  = (float)(3.0 * M_LN10 / om2sq * (om2sq / 6.0));
    const float BETA_F   = (float)(3.0 * M_LN10 / om2sq * (1.0 - 1.0 / 6.0));
    const float MAX_OM_F = (float)(10000.0 * 2.0 * M_PI);
    const float MIN_OM_F = (float)(20.0 * 2.0 * M_PI);
    const float KK_F     = (float)((1.0 / 44100.0) * (1.0 / 44100.0));

    float mu   = (softplusf(mu_raw[0])   + 1e-4f) * 2.43f;
    float Dmu  = (softplusf(Dmu_raw[0])  + 1e-4f) * 0.002452f;
    float T0mu = (softplusf(T0mu_raw[0]) + 1e-4f) * 0.004115f;
    float Ly   = 1.1f + 2.9f * sigmoidf(Ly_raw[0]);
    float xo   = 0.245f + 0.255f * sigmoidf(xo_raw[0]);
    float yo   = __fadd_rn(__fmul_rn(0.51f, Ly),
                           __fmul_rn(__fmul_rn(0.49f, Ly), sigmoidf(yo_raw[0])));

    float mf = (float)(id / 80 + 1);
    float nf = (float)(id % 80 + 1);

    float am = __fmul_rn(__fmul_rn(mf, PI_F), 2.0f);
    float bn = __fdiv_rn(__fmul_rn(nf, PI_F), Ly);
    float g1 = __fadd_rn(__fmul_rn(am, am), __fmul_rn(bn, bn));
    float omega_sq = __fadd_rn(__fmul_rn(T0mu, g1),
                               __fmul_rn(__fmul_rn(Dmu, g1), g1));
    float omega = sqrtf(fmaxf(omega_sq, 0.0f));
    float valid = (omega <= MAX_OM_F && omega >= MIN_OM_F) ? 1.0f : 0.0f;

    float xi_pi = (float)(0.05 * M_PI);
    float yi = __fmul_rn(0.1f, Ly);
    float InW = __fmul_rn(
        cosf(__fmul_rn(__fmul_rn(xi_pi, mf), 2.0f)),
        cosf(__fdiv_rn(__fmul_rn(__fmul_rn(yi, PI_F), nf), Ly)));
    float OutW = __fmul_rn(
        cosf(__fmul_rn(__fmul_rn(__fmul_rn(xo, PI_F), mf), 2.0f)),
        cosf(__fdiv_rn(__fmul_rn(__fmul_rn(yo, PI_F), nf), Ly)));

    float sigma = __fadd_rn(ALPHA_F, __fmul_rn(BETA_F, __fmul_rn(omega, omega)));
    float ms = __fmul_rn(__fmul_rn(__fmul_rn(0.25f, mu), 0.5f), Ly);
    float P = __fmul_rn(
        __fdiv_rn(__fmul_rn(__fmul_rn(__fmul_rn(OutW, InW), KK_F),
                            expf(__fmul_rn(-sigma, KF))),
                  ms),
        valid);
    float den = __fadd_rn(sinf(__fmul_rn(omega, KF)), 1e-8f);
    float A = __fdiv_rn(P, den);

    const double Kd = 1.0 / 44100.0;
    double th = (double)omega * Kd;
    double dd = exp(-(double)sigma * Kd);
    wsA[id]  = A;
    wsW[id]  = omega;
    wsS[id]  = sigma;
    wsCW[id] = (float)(dd * cos(th));
    wsSW[id] = (float)(dd * sin(th));
}

// R11-verified best (90.2 µs): R9 structure (grid, LDS layout, reduce,
// atomicAdd) with the Goertzel 2-term resonator rotation:
//   y_{n+1} = c1*y_n - c2*y_{n-1},  c1 = 2*d*cos(th) = 2*CW,  c2 = d*d.
// Init is the verified sincos path: y0 = env*sin(t0*th), and
// y1 = fma(S, CW, C*SW). Each tile re-seeds from f64 phase, so recurrence
// error spans only 42 steps.
__global__ __launch_bounds__(TB) void accum_kernel(
    const float* __restrict__ wsA,
    const float* __restrict__ wsW,
    const float* __restrict__ wsS,
    const float* __restrict__ wsCW,
    const float* __restrict__ wsSW,
    float* __restrict__ out, int T)
{
    __shared__ __align__(16) float lds[TC][TB + 2];

    const int tid  = threadIdx.x;
    const int t0   = blockIdx.x * TC;
    const int base = blockIdx.y * (TB * MPT);

    const float  KF     = 1.0f / 44100.0f;
    const double Kd     = 1.0 / 44100.0;
    const double TWO_PI = 6.283185307179586476925286766559;
    const double I2PI   = 0.15915494309189533576888376337251;

    v2f Y0[NPAIR], Y1[NPAIR], C1[NPAIR], C2[NPAIR];
    #pragma unroll
    for (int p = 0; p < NPAIR; ++p) {
        int m = base + p * (TB * 2) + tid * 2;     // even -> 8B aligned
        v2f CW = *(const v2f*)(wsCW + m);
        v2f SW = *(const v2f*)(wsSW + m);
        v2f A  = *(const v2f*)(wsA + m);
        v2f w  = *(const v2f*)(wsW + m);
        v2f sg = *(const v2f*)(wsS + m);
        v2f S, C;
        #pragma unroll
        for (int k = 0; k < 2; ++k) {
            double ph = (double)t0 * (double)w[k] * Kd;
            double q  = rint(ph * I2PI);
            float  r  = (float)fma(-q, TWO_PI, ph);
            float s0, c0;
            __sincosf(r, &s0, &c0);
            float env = A[k] * __expf(-sg[k] * (float)(t0 - 1) * KF);
            S[k] = env * s0;
            C[k] = env * c0;
        }
        Y0[p] = S;                                          // v_{t0}
        Y1[p] = __builtin_elementwise_fma(S, CW, C * SW);   // v_{t0+1}
        C1[p] = CW + CW;                                    // 2 d cos(th)
        C2[p] = __builtin_elementwise_fma(CW, CW, SW * SW); // d^2
    }

    #pragma unroll 1
    for (int it = 0; it < TC; it += BATCH) {
        #pragma unroll
        for (int b = 0; b < BATCH; ++b) {
            // per-thread (10-mode) partial for sample t0+it+b (current = Y0)
            v2f s01 = Y0[0] + Y0[1];
            v2f s23 = Y0[2] + Y0[3];
            v2f sp  = (s01 + s23) + Y0[4];
            lds[it + b][tid] = sp[0] + sp[1];
            // advance: y_{n+1} = c1*y_n - c2*y_{n-1}  (2 packed ops per pair)
            #pragma unroll
            for (int p = 0; p < NPAIR; ++p) {
                v2f yn = __builtin_elementwise_fma(C1[p], Y1[p], -(C2[p] * Y0[p]));
                Y0[p] = Y1[p];
                Y1[p] = yn;
            }
        }
    }
    __syncthreads();

    const int wv   = tid >> 6;
    const int lane = tid & 63;
    if (lane < TC / 2) {
        int s = wv * (TC / 2) + lane;              // wave 0: 0..20, wave 1: 21..41
        v2f z = {0.0f, 0.0f};
        #pragma unroll
        for (int r = 0; r < TB / 2; ++r)
            z += *(const v2f*)&lds[s][2 * r];
        int t = t0 + s;
        if (t < T) atomicAdd(&out[t], z[0] + z[1]);
    }
}

// R9/R11-field-verified fused max+div: 44 uniform co-resident blocks, local
// max from registers -> atomicMax(peak) -> release-add(done) -> short acquire
// poll -> divide own segment from registers already loaded.
__global__ __launch_bounds__(NORMB) void norm_kernel(
    float* __restrict__ out,
    unsigned int* peak,
    unsigned int* done, int T, int nblk)
{
    __shared__ float red[NORMB / 64];
    __shared__ float pks;

    int i = blockIdx.x * NORMB + threadIdx.x;      // pair index
    v2f v = {0.0f, 0.0f};
    bool full = (2 * i + 1 < T), half = (!full && 2 * i < T);
    if (full)      v = *(const v2f*)(out + 2 * i);
    else if (half) v[0] = out[2 * i];

    float mx = fmaxf(fabsf(v[0]), fabsf(v[1]));
    #pragma unroll
    for (int off = 32; off > 0; off >>= 1)
        mx = fmaxf(mx, __shfl_xor(mx, off, 64));
    int lane = threadIdx.x & 63, wv = threadIdx.x >> 6;
    if (lane == 0) red[wv] = mx;
    __syncthreads();

    if (threadIdx.x == 0) {
        float m = red[0];
        #pragma unroll
        for (int k = 1; k < NORMB / 64; ++k) m = fmaxf(m, red[k]);
        atomicMax(peak, __float_as_uint(m));       // m >= 0: bits monotone
        __hip_atomic_fetch_add(done, 1u, __ATOMIC_RELEASE,
                               __HIP_MEMORY_SCOPE_AGENT);
        unsigned int x;
        do {
            __builtin_amdgcn_s_sleep(2);
            x = __hip_atomic_load(done, __ATOMIC_ACQUIRE,
                                  __HIP_MEMORY_SCOPE_AGENT);
        } while (x < (unsigned int)nblk);
        pks = __uint_as_float(__hip_atomic_load(peak, __ATOMIC_RELAXED,
                                                __HIP_MEMORY_SCOPE_AGENT)) + 1e-8f;
    }
    __syncthreads();

    float pk = pks;
    if (full) {
        v[0] = __fdiv_rn(v[0], pk);
        v[1] = __fdiv_rn(v[1], pk);
        *(v2f*)(out + 2 * i) = v;
    } else if (half) {
        out[2 * i] = __fdiv_rn(v[0], pk);
    }
}

extern "C" void kernel_launch(void* const* d_in, const int* in_sizes, int n_in,
                              void* d_out, int out_size, void* d_ws, size_t ws_size,
                              hipStream_t stream)
{
    const float* mu   = (const float*)d_in[0];
    const float* Dmu  = (const float*)d_in[1];
    const float* T0mu = (const float*)d_in[2];
    const float* Lyr  = (const float*)d_in[3];
    const float* xor_ = (const float*)d_in[4];
    const float* yor_ = (const float*)d_in[5];
    float* out = (float*)d_out;

    float* ws   = (float*)d_ws;
    float* wsA  = ws;
    float* wsW  = ws + NMODES;
    float* wsS  = ws + 2 * NMODES;
    float* wsCW = ws + 3 * NMODES;
    float* wsSW = ws + 4 * NMODES;
    unsigned int* peak = (unsigned int*)(ws + 5 * NMODES);
    unsigned int* done = (unsigned int*)(ws + 5 * NMODES + 1);

    int T = out_size;
    int tchunks = (T + TC - 1) / TC;               // 525 at T=22050
    int npairs  = (T + 1) / 2;
    int nblk    = (npairs + NORMB - 1) / NORMB;    // 44 at T=22050

    setup_zero_kernel<<<(NMODES + 255) / 256, 256, 0, stream>>>(
        mu, Dmu, T0mu, Lyr, xor_, yor_, wsA, wsW, wsS, wsCW, wsSW,
        peak, done, out, T);
    accum_kernel<<<dim3(tchunks, MG), TB, 0, stream>>>(
        wsA, wsW, wsS, wsCW, wsSW, out, T);
    norm_kernel<<<nblk, NORMB, 0, stream>>>(out, peak, done, T, nblk);
}